// Round 5
// baseline (1453.946 us; speedup 1.0000x reference)
//
#include <hip/hip_runtime.h>

// Problem constants
#define B_    1024
#define C_    128
#define ELL   16
#define EQ    3
#define E_    10
#define P3    23
#define P2    5
#define NJI   12288          // EQ*ELL*ELL*ELL
#define RPAD  260            // padded row stride in floats (260%32==4)
#define CSL   (48 * RPAD)    // per-(e,c) padded V3 slice: 48 rows of 260 = 12480 floats

// ws layout (bytes)
#define WS_CNT   0
#define WS_LIST  64
#define WS_U3T   65536                          // mode-a: U3 transposed [k][ji]
#define WS_V3G   (2u << 20)                     // mode-b: V3 padded [e][c][48][260]
#define WS_NEED_B ((size_t)WS_V3G + (size_t)E_ * C_ * CSL * 4)

// ---------------------------------------------------------------------------
// Bucketing (shared logic): bucket batch indices by element, pad each bucket
// to x32 by replicating the last real index (k_main then needs no load guards;
// duplicate writes produce identical values or are guarded by cnt).
__device__ void do_lists(const float* __restrict__ y, int* __restrict__ cnt_g,
                         int* __restrict__ list_g, int t) {
    __shared__ int lcnt[E_];
    if (t < E_) lcnt[t] = 0;
    __syncthreads();
    for (int r = 0; r < 4; ++r) {
        int b = t + 256 * r;
        int e = 0;
        #pragma unroll
        for (int j = 1; j < E_; ++j)
            if (y[b * E_ + j] > 0.5f) e = j;
        int slot = atomicAdd(&lcnt[e], 1);
        list_g[e * B_ + slot] = b;
    }
    __syncthreads();
    if (t < E_) {
        int c0 = lcnt[t];
        cnt_g[t] = c0;
        int last = (c0 > 0) ? list_g[t * B_ + c0 - 1] : 0;
        int cp = (c0 + 31) & ~31;
        for (int s2 = c0; s2 < cp; ++s2) list_g[t * B_ + s2] = last;
    }
}

// ---------------------------------------------------------------------------
// K2 (mode b) + fused bucketing.
// v3g (padded layout) [(e*C+c)*CSL + (ji>>8)*RPAD + (ji&255)] =
//     sum_k U3[ji*23+k] * wmax[(e*23+k)*128+c]
// grid (25, E, 4): bx<24 are ji-tiles of 512; block (24,0,0) does bucketing.
__global__ __launch_bounds__(256, 4) void k_v3g(const float* __restrict__ U3,
                                                const float* __restrict__ wmax,
                                                const float* __restrict__ y,
                                                float* __restrict__ v3g,
                                                int* __restrict__ cnt_g,
                                                int* __restrict__ list_g) {
    const int t = threadIdx.x;
    if (blockIdx.x == 24) {
        if (blockIdx.y == 0 && blockIdx.z == 0) do_lists(y, cnt_g, list_g, t);
        return;
    }
    __shared__ __align__(16) float wsm[P3 * 32];
    const int jibase = blockIdx.x * 512;
    const int e  = blockIdx.y;
    const int cq = blockIdx.z;          // c-quarter

    for (int idx = t; idx < P3 * 32; idx += 256) {
        int k = idx >> 5, cc = idx & 31;
        wsm[idx] = wmax[(e * P3 + k) * C_ + cq * 32 + cc];
    }

    // rows ji0, ji0+1 of U3 = 46 consecutive floats at ji0*23
    const int ji0 = jibase + 2 * t;
    float u46[46];
    const float* up = U3 + (size_t)ji0 * P3;
    #pragma unroll
    for (int q = 0; q < 46; ++q) u46[q] = up[q];
    __syncthreads();

    const int row = ji0 >> 8, off = ji0 & 255;
    float* vbase = v3g + (size_t)(e * C_ + cq * 32) * CSL + row * RPAD + off;
    #pragma unroll
    for (int g = 0; g < 8; ++g) {
        float a0[4], a1[4];
        #pragma unroll
        for (int q = 0; q < 4; ++q) { a0[q] = 0.f; a1[q] = 0.f; }
        #pragma unroll
        for (int k = 0; k < P3; ++k) {
            float4 wk = *(const float4*)&wsm[k * 32 + g * 4];
            a0[0] += u46[k] * wk.x; a1[0] += u46[23 + k] * wk.x;
            a0[1] += u46[k] * wk.y; a1[1] += u46[23 + k] * wk.y;
            a0[2] += u46[k] * wk.z; a1[2] += u46[23 + k] * wk.z;
            a0[3] += u46[k] * wk.w; a1[3] += u46[23 + k] * wk.w;
        }
        #pragma unroll
        for (int q = 0; q < 4; ++q) {
            float2 o; o.x = a0[q]; o.y = a1[q];
            *(float2*)(vbase + (size_t)(g * 4 + q) * CSL) = o;
        }
    }
}

// ---------------------------------------------------------------------------
// K2 (mode a): transpose U3 [ji][k] -> U3T [k][ji]; block 1104 does bucketing.
__global__ void k_transposeU3(const float* __restrict__ U3, float* __restrict__ U3T,
                              const float* __restrict__ y, int* __restrict__ cnt_g,
                              int* __restrict__ list_g) {
    if (blockIdx.x == 1104) { do_lists(y, cnt_g, list_g, threadIdx.x); return; }
    int o = blockIdx.x * 256 + threadIdx.x;
    if (o < NJI * P3) {
        int ji = o / P3, k = o - ji * P3;
        U3T[k * NJI + ji] = U3[o];
    }
}

// ---------------------------------------------------------------------------
// K3: main contraction. grid (C_*EQ, E_), 256 threads (4 waves).
// bx = c*3+w. xx = t&15 (x2 partition, consecutive lanes), bs = t>>4 in
// [0,16); 2 batch rows per thread -> chunk = 32 rows. V3 slice in LDS with
// row stride 260 (16 rows/wave -> 2-way bank aliasing = free). nu=1
// reduction over x2 via width-16 shfl_xor: NO barriers in the chunk loop.
__global__ __launch_bounds__(256, 4) void k_main(
    const float* __restrict__ x, const float* __restrict__ u3x,
    const float* __restrict__ U2, const float* __restrict__ U1,
    const float* __restrict__ wmax, const float* __restrict__ w2,
    const float* __restrict__ w1, const int* __restrict__ cnt_g,
    const int* __restrict__ list_g, float* __restrict__ out, int mode_b) {

    __shared__ __align__(16) float V3L[16 * RPAD];  // 16,640 B

    const int t  = threadIdx.x;
    const int bx = blockIdx.x;
    const int w  = bx % 3, c = bx / 3;
    const int e  = blockIdx.y;
    const int xx = t & 15, bs = t >> 4;
    const int cnt  = cnt_g[e];
    const int cntp = (cnt + 31) & ~31;

    // ---- fill V3L ----
    if (mode_b) {
        // v3g already stored pre-swizzled: straight contiguous copy (1040 f4)
        const float4* src = (const float4*)(u3x + (size_t)(e * C_ + c) * CSL
                                            + (size_t)w * 16 * RPAD);
        float4* dst = (float4*)V3L;
        #pragma unroll
        for (int r = 0; r < 4; ++r) dst[t + 256 * r] = src[t + 256 * r];
        if (t < 16) dst[1024 + t] = src[1024 + t];
    } else {
        // compute from U3T [k][NJI], columns w*4096 .. +4096
        #pragma unroll
        for (int r = 0; r < 4; ++r) {
            int f = t + 256 * r;
            float4 acc = make_float4(0.f, 0.f, 0.f, 0.f);
            for (int k = 0; k < P3; ++k) {
                float wm = wmax[(e * P3 + k) * C_ + c];
                float4 u = ((const float4*)(u3x + (size_t)k * NJI + w * 4096))[f];
                acc.x += u.x * wm; acc.y += u.y * wm;
                acc.z += u.z * wm; acc.w += u.w * wm;
            }
            int ji0 = 4 * f;
            *(float4*)(&V3L[(ji0 >> 8) * RPAD + (ji0 & 255)]) = acc;
        }
    }

    // ---- v2r[v] = sum_k U2[(w,xx,v),k]*w2[e,k,c] ----
    float w2r[P2];
    #pragma unroll
    for (int k = 0; k < P2; ++k) w2r[k] = w2[(e * P2 + k) * C_ + c];
    float v2r[16];
    {
        const float* u2p = U2 + (size_t)(w * 256 + xx * 16) * P2;
        #pragma unroll
        for (int v = 0; v < 16; ++v) {
            float s = 0.f;
            #pragma unroll
            for (int k = 0; k < P2; ++k) s += u2p[v * P2 + k] * w2r[k];
            v2r[v] = s;
        }
    }
    // nu=1 coefficient at this thread's own x2 position only
    const float v1x = U1[w * 16 + xx] * w1[e * C_ + c];
    __syncthreads();

    const float* v3p = &V3L[xx * RPAD];

    // ---- chunk loop: 32 rows per chunk, 2 per thread, no barriers ----
    for (int base = 0; base < cntp; base += 32) {
        const int slot = base + bs * 2;
        const int b0 = list_g[e * B_ + slot];
        const int b1 = list_g[e * B_ + slot + 1];
        const float* xb0 = x + ((size_t)b0 * C_ + c) * ELL;
        const float* xb1 = x + ((size_t)b1 * C_ + c) * ELL;

        float xr0[16], xr1[16];
        #pragma unroll
        for (int i4 = 0; i4 < 4; ++i4) {
            float4 a = ((const float4*)xb0)[i4];
            float4 b = ((const float4*)xb1)[i4];
            xr0[4 * i4 + 0] = a.x; xr0[4 * i4 + 1] = a.y;
            xr0[4 * i4 + 2] = a.z; xr0[4 * i4 + 3] = a.w;
            xr1[4 * i4 + 0] = b.x; xr1[4 * i4 + 1] = b.y;
            xr1[4 * i4 + 2] = b.z; xr1[4 * i4 + 3] = b.w;
        }
        const float xo0 = xb0[xx];   // own-x2 element (L1 hit)
        const float xo1 = xb1[xx];

        float t20 = 0.f, t21 = 0.f;
        #pragma unroll
        for (int v = 0; v < 16; ++v) {
            float s0 = v2r[v], s1 = v2r[v];
            #pragma unroll
            for (int i4 = 0; i4 < 4; ++i4) {
                float4 u = *(const float4*)(v3p + v * 16 + 4 * i4);
                s0 += u.x * xr0[4 * i4 + 0]; s1 += u.x * xr1[4 * i4 + 0];
                s0 += u.y * xr0[4 * i4 + 1]; s1 += u.y * xr1[4 * i4 + 1];
                s0 += u.z * xr0[4 * i4 + 2]; s1 += u.z * xr1[4 * i4 + 2];
                s0 += u.w * xr0[4 * i4 + 3]; s1 += u.w * xr1[4 * i4 + 3];
            }
            t20 += s0 * xr0[v];
            t21 += s1 * xr1[v];
        }

        // out[b] = sum_xx (t2 + v1[xx]) * x[xx]  -- width-16 butterfly
        float c0v = (t20 + v1x) * xo0;
        float c1v = (t21 + v1x) * xo1;
        #pragma unroll
        for (int m = 1; m < 16; m <<= 1) {
            c0v += __shfl_xor(c0v, m, 16);
            c1v += __shfl_xor(c1v, m, 16);
        }
        if (xx == 0) {
            if (slot < cnt)
                out[(size_t)b0 * (C_ * EQ) + c * EQ + w] = c0v;
            if (slot + 1 < cnt)
                out[(size_t)b1 * (C_ * EQ) + c * EQ + w] = c1v;
        }
    }
}

// ---------------------------------------------------------------------------
extern "C" void kernel_launch(void* const* d_in, const int* in_sizes, int n_in,
                              void* d_out, int out_size, void* d_ws, size_t ws_size,
                              hipStream_t stream) {
    const float* x    = (const float*)d_in[0];
    const float* y    = (const float*)d_in[1];
    const float* U3   = (const float*)d_in[2];
    const float* U2   = (const float*)d_in[3];
    const float* U1   = (const float*)d_in[4];
    const float* wmax = (const float*)d_in[5];
    const float* w2   = (const float*)d_in[6];
    const float* w1   = (const float*)d_in[7];
    float* out = (float*)d_out;
    char*  ws  = (char*)d_ws;

    int* cnt_g  = (int*)(ws + WS_CNT);
    int* list_g = (int*)(ws + WS_LIST);

    if (ws_size >= WS_NEED_B) {
        float* v3g = (float*)(ws + WS_V3G);
        k_v3g<<<dim3(25, E_, 4), 256, 0, stream>>>(U3, wmax, y, v3g, cnt_g, list_g);
        k_main<<<dim3(C_ * EQ, E_), 256, 0, stream>>>(x, v3g, U2, U1, wmax, w2, w1,
                                                      cnt_g, list_g, out, 1);
    } else {
        float* u3t = (float*)(ws + WS_U3T);
        k_transposeU3<<<1105, 256, 0, stream>>>(U3, u3t, y, cnt_g, list_g);
        k_main<<<dim3(C_ * EQ, E_), 256, 0, stream>>>(x, u3t, U2, U1, wmax, w2, w1,
                                                      cnt_g, list_g, out, 0);
    }
}

// Round 6
// 1119.764 us; speedup vs baseline: 1.2984x; 1.2984x over previous
//
#include <hip/hip_runtime.h>

// Problem constants
#define B_    1024
#define C_    128
#define ELL   16
#define EQ    3
#define E_    10
#define P3    23
#define P2    5
#define NJI   12288          // EQ*ELL*ELL*ELL
#define RPAD  260            // padded row stride in floats (260%32==4)
#define CSL   (48 * RPAD)    // per-(e,c) padded V3 slice: 48 rows of 260 = 12480 floats

// ws layout (bytes)
#define WS_CNT   0
#define WS_LIST  64
#define WS_U3T   65536                          // mode-a: U3 transposed [k][ji]
#define WS_V3G   (2u << 20)                     // mode-b: V3 padded [e][c][48][260]
#define WS_NEED_B ((size_t)WS_V3G + (size_t)E_ * C_ * CSL * 4)

// ---------------------------------------------------------------------------
// Bucketing: bucket batch indices by element, pad each bucket to x32 by
// replicating the last real index (k_main then needs no load guards).
__device__ void do_lists(const float* __restrict__ y, int* __restrict__ cnt_g,
                         int* __restrict__ list_g, int t) {
    __shared__ int lcnt[E_];
    if (t < E_) lcnt[t] = 0;
    __syncthreads();
    for (int r = 0; r < 4; ++r) {
        int b = t + 256 * r;
        int e = 0;
        #pragma unroll
        for (int j = 1; j < E_; ++j)
            if (y[b * E_ + j] > 0.5f) e = j;
        int slot = atomicAdd(&lcnt[e], 1);
        list_g[e * B_ + slot] = b;
    }
    __syncthreads();
    if (t < E_) {
        int c0 = lcnt[t];
        cnt_g[t] = c0;
        int last = (c0 > 0) ? list_g[t * B_ + c0 - 1] : 0;
        int cp = (c0 + 31) & ~31;
        for (int s2 = c0; s2 < cp; ++s2) list_g[t * B_ + s2] = last;
    }
}

// ---------------------------------------------------------------------------
// K2 (mode b) + fused bucketing.
// v3g (padded layout) [(e*C+c)*CSL + (ji>>8)*RPAD + (ji&255)] =
//     sum_k U3[ji*23+k] * wmax[(e*23+k)*128+c]
// grid (25, E, 4): bx<24 are ji-tiles of 512; block (24,0,0) does bucketing.
__global__ __launch_bounds__(256, 4) void k_v3g(const float* __restrict__ U3,
                                                const float* __restrict__ wmax,
                                                const float* __restrict__ y,
                                                float* __restrict__ v3g,
                                                int* __restrict__ cnt_g,
                                                int* __restrict__ list_g) {
    const int t = threadIdx.x;
    if (blockIdx.x == 24) {
        if (blockIdx.y == 0 && blockIdx.z == 0) do_lists(y, cnt_g, list_g, t);
        return;
    }
    __shared__ __align__(16) float wsm[P3 * 32];
    const int jibase = blockIdx.x * 512;
    const int e  = blockIdx.y;
    const int cq = blockIdx.z;          // c-quarter

    for (int idx = t; idx < P3 * 32; idx += 256) {
        int k = idx >> 5, cc = idx & 31;
        wsm[idx] = wmax[(e * P3 + k) * C_ + cq * 32 + cc];
    }

    // rows ji0, ji0+1 of U3 = 46 consecutive floats at ji0*23
    const int ji0 = jibase + 2 * t;
    float u46[46];
    const float* up = U3 + (size_t)ji0 * P3;
    #pragma unroll
    for (int q = 0; q < 46; ++q) u46[q] = up[q];
    __syncthreads();

    const int row = ji0 >> 8, off = ji0 & 255;
    float* vbase = v3g + (size_t)(e * C_ + cq * 32) * CSL + row * RPAD + off;
    #pragma unroll
    for (int g = 0; g < 8; ++g) {
        float a0[4], a1[4];
        #pragma unroll
        for (int q = 0; q < 4; ++q) { a0[q] = 0.f; a1[q] = 0.f; }
        #pragma unroll
        for (int k = 0; k < P3; ++k) {
            float4 wk = *(const float4*)&wsm[k * 32 + g * 4];
            a0[0] += u46[k] * wk.x; a1[0] += u46[23 + k] * wk.x;
            a0[1] += u46[k] * wk.y; a1[1] += u46[23 + k] * wk.y;
            a0[2] += u46[k] * wk.z; a1[2] += u46[23 + k] * wk.z;
            a0[3] += u46[k] * wk.w; a1[3] += u46[23 + k] * wk.w;
        }
        #pragma unroll
        for (int q = 0; q < 4; ++q) {
            float2 o; o.x = a0[q]; o.y = a1[q];
            *(float2*)(vbase + (size_t)(g * 4 + q) * CSL) = o;
        }
    }
}

// ---------------------------------------------------------------------------
// K2 (mode a): transpose U3 [ji][k] -> U3T [k][ji]; block 1104 does bucketing.
__global__ void k_transposeU3(const float* __restrict__ U3, float* __restrict__ U3T,
                              const float* __restrict__ y, int* __restrict__ cnt_g,
                              int* __restrict__ list_g) {
    if (blockIdx.x == 1104) { do_lists(y, cnt_g, list_g, threadIdx.x); return; }
    int o = blockIdx.x * 256 + threadIdx.x;
    if (o < NJI * P3) {
        int ji = o / P3, k = o - ji * P3;
        U3T[k * NJI + ji] = U3[o];
    }
}

// ---------------------------------------------------------------------------
// K3: main contraction. grid (C_*EQ, E_), 256 threads (4 waves).
// bx = c*3+w. xx = t&15 (x2 partition, consecutive lanes), bs = t>>4 in
// [0,16); 2 batch rows per thread -> chunk = 32 rows. V3 slice in LDS with
// row stride 260 (16 rows/wave -> 2-way bank aliasing = free). nu=1
// reduction over x2 via width-16 shfl_xor: NO barriers in the chunk loop.
// launch_bounds(256,2): 256-VGPR cap. (256,4)'s 128-VGPR cap made the
// allocator spill xr to scratch -> 4.8 GB of HBM spill traffic (round 5).
__global__ __launch_bounds__(256, 2) void k_main(
    const float* __restrict__ x, const float* __restrict__ u3x,
    const float* __restrict__ U2, const float* __restrict__ U1,
    const float* __restrict__ wmax, const float* __restrict__ w2,
    const float* __restrict__ w1, const int* __restrict__ cnt_g,
    const int* __restrict__ list_g, float* __restrict__ out, int mode_b) {

    __shared__ __align__(16) float V3L[16 * RPAD];  // 16,640 B

    const int t  = threadIdx.x;
    const int bx = blockIdx.x;
    const int w  = bx % 3, c = bx / 3;
    const int e  = blockIdx.y;
    const int xx = t & 15, bs = t >> 4;
    const int cnt  = cnt_g[e];
    const int cntp = (cnt + 31) & ~31;

    // ---- fill V3L ----
    if (mode_b) {
        // v3g already stored pre-swizzled: straight contiguous copy (1040 f4)
        const float4* src = (const float4*)(u3x + (size_t)(e * C_ + c) * CSL
                                            + (size_t)w * 16 * RPAD);
        float4* dst = (float4*)V3L;
        #pragma unroll
        for (int r = 0; r < 4; ++r) dst[t + 256 * r] = src[t + 256 * r];
        if (t < 16) dst[1024 + t] = src[1024 + t];
    } else {
        // compute from U3T [k][NJI], columns w*4096 .. +4096
        #pragma unroll
        for (int r = 0; r < 4; ++r) {
            int f = t + 256 * r;
            float4 acc = make_float4(0.f, 0.f, 0.f, 0.f);
            for (int k = 0; k < P3; ++k) {
                float wm = wmax[(e * P3 + k) * C_ + c];
                float4 u = ((const float4*)(u3x + (size_t)k * NJI + w * 4096))[f];
                acc.x += u.x * wm; acc.y += u.y * wm;
                acc.z += u.z * wm; acc.w += u.w * wm;
            }
            int ji0 = 4 * f;
            *(float4*)(&V3L[(ji0 >> 8) * RPAD + (ji0 & 255)]) = acc;
        }
    }

    // ---- v2r[v] = sum_k U2[(w,xx,v),k]*w2[e,k,c] ----
    float w2r[P2];
    #pragma unroll
    for (int k = 0; k < P2; ++k) w2r[k] = w2[(e * P2 + k) * C_ + c];
    float v2r[16];
    {
        const float* u2p = U2 + (size_t)(w * 256 + xx * 16) * P2;
        #pragma unroll
        for (int v = 0; v < 16; ++v) {
            float s = 0.f;
            #pragma unroll
            for (int k = 0; k < P2; ++k) s += u2p[v * P2 + k] * w2r[k];
            v2r[v] = s;
        }
    }
    // nu=1 coefficient at this thread's own x2 position only
    const float v1x = U1[w * 16 + xx] * w1[e * C_ + c];
    __syncthreads();

    const float* v3p = &V3L[xx * RPAD];

    // ---- chunk loop: 32 rows per chunk, 2 per thread, no barriers ----
    for (int base = 0; base < cntp; base += 32) {
        const int slot = base + bs * 2;
        const int b0 = list_g[e * B_ + slot];
        const int b1 = list_g[e * B_ + slot + 1];
        const float* xb0 = x + ((size_t)b0 * C_ + c) * ELL;
        const float* xb1 = x + ((size_t)b1 * C_ + c) * ELL;

        float xr0[16], xr1[16];
        #pragma unroll
        for (int i4 = 0; i4 < 4; ++i4) {
            float4 a = ((const float4*)xb0)[i4];
            float4 b = ((const float4*)xb1)[i4];
            xr0[4 * i4 + 0] = a.x; xr0[4 * i4 + 1] = a.y;
            xr0[4 * i4 + 2] = a.z; xr0[4 * i4 + 3] = a.w;
            xr1[4 * i4 + 0] = b.x; xr1[4 * i4 + 1] = b.y;
            xr1[4 * i4 + 2] = b.z; xr1[4 * i4 + 3] = b.w;
        }
        const float xo0 = xb0[xx];   // own-x2 element (L1 hit)
        const float xo1 = xb1[xx];

        float t20 = 0.f, t21 = 0.f;
        #pragma unroll
        for (int v = 0; v < 16; ++v) {
            float s0 = v2r[v], s1 = v2r[v];
            #pragma unroll
            for (int i4 = 0; i4 < 4; ++i4) {
                float4 u = *(const float4*)(v3p + v * 16 + 4 * i4);
                s0 += u.x * xr0[4 * i4 + 0]; s1 += u.x * xr1[4 * i4 + 0];
                s0 += u.y * xr0[4 * i4 + 1]; s1 += u.y * xr1[4 * i4 + 1];
                s0 += u.z * xr0[4 * i4 + 2]; s1 += u.z * xr1[4 * i4 + 2];
                s0 += u.w * xr0[4 * i4 + 3]; s1 += u.w * xr1[4 * i4 + 3];
            }
            t20 += s0 * xr0[v];
            t21 += s1 * xr1[v];
        }

        // out[b] = sum_xx (t2 + v1[xx]) * x[xx]  -- width-16 butterfly
        float c0v = (t20 + v1x) * xo0;
        float c1v = (t21 + v1x) * xo1;
        #pragma unroll
        for (int m = 1; m < 16; m <<= 1) {
            c0v += __shfl_xor(c0v, m, 16);
            c1v += __shfl_xor(c1v, m, 16);
        }
        if (xx == 0) {
            if (slot < cnt)
                out[(size_t)b0 * (C_ * EQ) + c * EQ + w] = c0v;
            if (slot + 1 < cnt)
                out[(size_t)b1 * (C_ * EQ) + c * EQ + w] = c1v;
        }
    }
}

// ---------------------------------------------------------------------------
extern "C" void kernel_launch(void* const* d_in, const int* in_sizes, int n_in,
                              void* d_out, int out_size, void* d_ws, size_t ws_size,
                              hipStream_t stream) {
    const float* x    = (const float*)d_in[0];
    const float* y    = (const float*)d_in[1];
    const float* U3   = (const float*)d_in[2];
    const float* U2   = (const float*)d_in[3];
    const float* U1   = (const float*)d_in[4];
    const float* wmax = (const float*)d_in[5];
    const float* w2   = (const float*)d_in[6];
    const float* w1   = (const float*)d_in[7];
    float* out = (float*)d_out;
    char*  ws  = (char*)d_ws;

    int* cnt_g  = (int*)(ws + WS_CNT);
    int* list_g = (int*)(ws + WS_LIST);

    if (ws_size >= WS_NEED_B) {
        float* v3g = (float*)(ws + WS_V3G);
        k_v3g<<<dim3(25, E_, 4), 256, 0, stream>>>(U3, wmax, y, v3g, cnt_g, list_g);
        k_main<<<dim3(C_ * EQ, E_), 256, 0, stream>>>(x, v3g, U2, U1, wmax, w2, w1,
                                                      cnt_g, list_g, out, 1);
    } else {
        float* u3t = (float*)(ws + WS_U3T);
        k_transposeU3<<<1105, 256, 0, stream>>>(U3, u3t, y, cnt_g, list_g);
        k_main<<<dim3(C_ * EQ, E_), 256, 0, stream>>>(x, u3t, U2, U1, wmax, w2, w1,
                                                      cnt_g, list_g, out, 0);
    }
}

// Round 7
// 156.791 us; speedup vs baseline: 9.2732x; 7.1418x over previous
//
#include <hip/hip_runtime.h>

// Problem constants
#define B_    1024
#define C_    128
#define ELL   16
#define EQ    3
#define E_    10
#define P3    23
#define P2    5
#define NJI   12288          // EQ*ELL*ELL*ELL
#define RPAD  260            // padded row stride in floats (260%32==4)
#define CSL   (48 * RPAD)    // per-(e,c) padded V3 slice: 48 rows of 260 = 12480 floats

// ws layout (bytes)
#define WS_CNT   0
#define WS_LIST  64
#define WS_U3T   65536                          // mode-a: U3 transposed [k][ji]
#define WS_V3G   (2u << 20)                     // mode-b: V3 padded [e][c][48][260]
#define WS_NEED_B ((size_t)WS_V3G + (size_t)E_ * C_ * CSL * 4)

// ---------------------------------------------------------------------------
// Bucketing: bucket batch indices by element, pad each bucket to x32 by
// replicating the last real index (k_main then needs no load guards).
__device__ void do_lists(const float* __restrict__ y, int* __restrict__ cnt_g,
                         int* __restrict__ list_g, int t) {
    __shared__ int lcnt[E_];
    if (t < E_) lcnt[t] = 0;
    __syncthreads();
    for (int r = 0; r < 4; ++r) {
        int b = t + 256 * r;
        int e = 0;
        #pragma unroll
        for (int j = 1; j < E_; ++j)
            if (y[b * E_ + j] > 0.5f) e = j;
        int slot = atomicAdd(&lcnt[e], 1);
        list_g[e * B_ + slot] = b;
    }
    __syncthreads();
    if (t < E_) {
        int c0 = lcnt[t];
        cnt_g[t] = c0;
        int last = (c0 > 0) ? list_g[t * B_ + c0 - 1] : 0;
        int cp = (c0 + 31) & ~31;
        for (int s2 = c0; s2 < cp; ++s2) list_g[t * B_ + s2] = last;
    }
}

// ---------------------------------------------------------------------------
// K2 (mode b) + fused bucketing.
// v3g (padded layout) [(e*C+c)*CSL + (ji>>8)*RPAD + (ji&255)] =
//     sum_k U3[ji*23+k] * wmax[(e*23+k)*128+c]
// grid (25, E, 4): bx<24 are ji-tiles of 512; block (24,0,0) does bucketing.
__global__ __launch_bounds__(256, 4) void k_v3g(const float* __restrict__ U3,
                                                const float* __restrict__ wmax,
                                                const float* __restrict__ y,
                                                float* __restrict__ v3g,
                                                int* __restrict__ cnt_g,
                                                int* __restrict__ list_g) {
    const int t = threadIdx.x;
    if (blockIdx.x == 24) {
        if (blockIdx.y == 0 && blockIdx.z == 0) do_lists(y, cnt_g, list_g, t);
        return;
    }
    __shared__ __align__(16) float wsm[P3 * 32];
    const int jibase = blockIdx.x * 512;
    const int e  = blockIdx.y;
    const int cq = blockIdx.z;          // c-quarter

    for (int idx = t; idx < P3 * 32; idx += 256) {
        int k = idx >> 5, cc = idx & 31;
        wsm[idx] = wmax[(e * P3 + k) * C_ + cq * 32 + cc];
    }

    // rows ji0, ji0+1 of U3 = 46 consecutive floats at ji0*23
    const int ji0 = jibase + 2 * t;
    float u46[46];
    const float* up = U3 + (size_t)ji0 * P3;
    #pragma unroll
    for (int q = 0; q < 46; ++q) u46[q] = up[q];
    __syncthreads();

    const int row = ji0 >> 8, off = ji0 & 255;
    float* vbase = v3g + (size_t)(e * C_ + cq * 32) * CSL + row * RPAD + off;
    #pragma unroll
    for (int g = 0; g < 8; ++g) {
        float a0[4], a1[4];
        #pragma unroll
        for (int q = 0; q < 4; ++q) { a0[q] = 0.f; a1[q] = 0.f; }
        #pragma unroll
        for (int k = 0; k < P3; ++k) {
            float4 wk = *(const float4*)&wsm[k * 32 + g * 4];
            a0[0] += u46[k] * wk.x; a1[0] += u46[23 + k] * wk.x;
            a0[1] += u46[k] * wk.y; a1[1] += u46[23 + k] * wk.y;
            a0[2] += u46[k] * wk.z; a1[2] += u46[23 + k] * wk.z;
            a0[3] += u46[k] * wk.w; a1[3] += u46[23 + k] * wk.w;
        }
        #pragma unroll
        for (int q = 0; q < 4; ++q) {
            float2 o; o.x = a0[q]; o.y = a1[q];
            *(float2*)(vbase + (size_t)(g * 4 + q) * CSL) = o;
        }
    }
}

// ---------------------------------------------------------------------------
// K2 (mode a): transpose U3 [ji][k] -> U3T [k][ji]; block 1104 does bucketing.
__global__ void k_transposeU3(const float* __restrict__ U3, float* __restrict__ U3T,
                              const float* __restrict__ y, int* __restrict__ cnt_g,
                              int* __restrict__ list_g) {
    if (blockIdx.x == 1104) { do_lists(y, cnt_g, list_g, threadIdx.x); return; }
    int o = blockIdx.x * 256 + threadIdx.x;
    if (o < NJI * P3) {
        int ji = o / P3, k = o - ji * P3;
        U3T[k * NJI + ji] = U3[o];
    }
}

// ---------------------------------------------------------------------------
// K3: main contraction. grid (C_*EQ, E_), 256 threads (4 waves).
// bx = c*3+w. xx = t&15 (x2 partition, consecutive lanes), bs = t>>4 in
// [0,16); 2 batch rows per thread -> chunk = 32 rows. V3 slice in LDS with
// row stride 260. nu=1 reduction over x2 via width-16 shfl_xor.
// CRITICAL: one __syncthreads() per chunk iteration. Without it (rounds 5/6)
// LICM hoists the loop-invariant V3L row (64 ds_read_b128 = 256 floats) out
// of the chunk loop -> liveness blows past the VGPR file -> xr spills to
// scratch -> 3.9 GB of HBM scratch traffic, 12x slowdown. The barrier blocks
// LDS-load hoisting (empirically verified: round 4 w/ barrier = no spill).
__global__ __launch_bounds__(256, 2) void k_main(
    const float* __restrict__ x, const float* __restrict__ u3x,
    const float* __restrict__ U2, const float* __restrict__ U1,
    const float* __restrict__ wmax, const float* __restrict__ w2,
    const float* __restrict__ w1, const int* __restrict__ cnt_g,
    const int* __restrict__ list_g, float* __restrict__ out, int mode_b) {

    __shared__ __align__(16) float V3L[16 * RPAD];  // 16,640 B

    const int t  = threadIdx.x;
    const int bx = blockIdx.x;
    const int w  = bx % 3, c = bx / 3;
    const int e  = blockIdx.y;
    const int xx = t & 15, bs = t >> 4;
    const int cnt  = cnt_g[e];
    const int cntp = (cnt + 31) & ~31;

    // ---- fill V3L ----
    if (mode_b) {
        // v3g already stored pre-swizzled: straight contiguous copy (1040 f4)
        const float4* src = (const float4*)(u3x + (size_t)(e * C_ + c) * CSL
                                            + (size_t)w * 16 * RPAD);
        float4* dst = (float4*)V3L;
        #pragma unroll
        for (int r = 0; r < 4; ++r) dst[t + 256 * r] = src[t + 256 * r];
        if (t < 16) dst[1024 + t] = src[1024 + t];
    } else {
        // compute from U3T [k][NJI], columns w*4096 .. +4096
        #pragma unroll
        for (int r = 0; r < 4; ++r) {
            int f = t + 256 * r;
            float4 acc = make_float4(0.f, 0.f, 0.f, 0.f);
            for (int k = 0; k < P3; ++k) {
                float wm = wmax[(e * P3 + k) * C_ + c];
                float4 u = ((const float4*)(u3x + (size_t)k * NJI + w * 4096))[f];
                acc.x += u.x * wm; acc.y += u.y * wm;
                acc.z += u.z * wm; acc.w += u.w * wm;
            }
            int ji0 = 4 * f;
            *(float4*)(&V3L[(ji0 >> 8) * RPAD + (ji0 & 255)]) = acc;
        }
    }

    // ---- v2r[v] = sum_k U2[(w,xx,v),k]*w2[e,k,c] ----
    float w2r[P2];
    #pragma unroll
    for (int k = 0; k < P2; ++k) w2r[k] = w2[(e * P2 + k) * C_ + c];
    float v2r[16];
    {
        const float* u2p = U2 + (size_t)(w * 256 + xx * 16) * P2;
        #pragma unroll
        for (int v = 0; v < 16; ++v) {
            float s = 0.f;
            #pragma unroll
            for (int k = 0; k < P2; ++k) s += u2p[v * P2 + k] * w2r[k];
            v2r[v] = s;
        }
    }
    // nu=1 coefficient at this thread's own x2 position only
    const float v1x = U1[w * 16 + xx] * w1[e * C_ + c];
    __syncthreads();

    const float* v3p = &V3L[xx * RPAD];

    // ---- chunk loop: 32 rows per chunk, 2 per thread ----
    #pragma clang loop unroll(disable)
    for (int base = 0; base < cntp; base += 32) {
        __syncthreads();   // blocks LICM of the V3L row reads (see header note)

        const int slot = base + bs * 2;
        const int b0 = list_g[e * B_ + slot];
        const int b1 = list_g[e * B_ + slot + 1];
        const float* xb0 = x + ((size_t)b0 * C_ + c) * ELL;
        const float* xb1 = x + ((size_t)b1 * C_ + c) * ELL;

        float xr0[16], xr1[16];
        #pragma unroll
        for (int i4 = 0; i4 < 4; ++i4) {
            float4 a = ((const float4*)xb0)[i4];
            float4 b = ((const float4*)xb1)[i4];
            xr0[4 * i4 + 0] = a.x; xr0[4 * i4 + 1] = a.y;
            xr0[4 * i4 + 2] = a.z; xr0[4 * i4 + 3] = a.w;
            xr1[4 * i4 + 0] = b.x; xr1[4 * i4 + 1] = b.y;
            xr1[4 * i4 + 2] = b.z; xr1[4 * i4 + 3] = b.w;
        }
        const float xo0 = xb0[xx];   // own-x2 element (L1 hit; NOT xr0[xx] --
        const float xo1 = xb1[xx];   // dynamic reg indexing would force scratch)

        float t20 = 0.f, t21 = 0.f;
        #pragma unroll
        for (int v = 0; v < 16; ++v) {
            float s0 = v2r[v], s1 = v2r[v];
            #pragma unroll
            for (int i4 = 0; i4 < 4; ++i4) {
                float4 u = *(const float4*)(v3p + v * 16 + 4 * i4);
                s0 += u.x * xr0[4 * i4 + 0]; s1 += u.x * xr1[4 * i4 + 0];
                s0 += u.y * xr0[4 * i4 + 1]; s1 += u.y * xr1[4 * i4 + 1];
                s0 += u.z * xr0[4 * i4 + 2]; s1 += u.z * xr1[4 * i4 + 2];
                s0 += u.w * xr0[4 * i4 + 3]; s1 += u.w * xr1[4 * i4 + 3];
            }
            t20 += s0 * xr0[v];
            t21 += s1 * xr1[v];
        }

        // out[b] = sum_xx (t2 + v1[xx]) * x[xx]  -- width-16 butterfly
        float c0v = (t20 + v1x) * xo0;
        float c1v = (t21 + v1x) * xo1;
        #pragma unroll
        for (int m = 1; m < 16; m <<= 1) {
            c0v += __shfl_xor(c0v, m, 16);
            c1v += __shfl_xor(c1v, m, 16);
        }
        if (xx == 0) {
            if (slot < cnt)
                out[(size_t)b0 * (C_ * EQ) + c * EQ + w] = c0v;
            if (slot + 1 < cnt)
                out[(size_t)b1 * (C_ * EQ) + c * EQ + w] = c1v;
        }
    }
}

// ---------------------------------------------------------------------------
extern "C" void kernel_launch(void* const* d_in, const int* in_sizes, int n_in,
                              void* d_out, int out_size, void* d_ws, size_t ws_size,
                              hipStream_t stream) {
    const float* x    = (const float*)d_in[0];
    const float* y    = (const float*)d_in[1];
    const float* U3   = (const float*)d_in[2];
    const float* U2   = (const float*)d_in[3];
    const float* U1   = (const float*)d_in[4];
    const float* wmax = (const float*)d_in[5];
    const float* w2   = (const float*)d_in[6];
    const float* w1   = (const float*)d_in[7];
    float* out = (float*)d_out;
    char*  ws  = (char*)d_ws;

    int* cnt_g  = (int*)(ws + WS_CNT);
    int* list_g = (int*)(ws + WS_LIST);

    if (ws_size >= WS_NEED_B) {
        float* v3g = (float*)(ws + WS_V3G);
        k_v3g<<<dim3(25, E_, 4), 256, 0, stream>>>(U3, wmax, y, v3g, cnt_g, list_g);
        k_main<<<dim3(C_ * EQ, E_), 256, 0, stream>>>(x, v3g, U2, U1, wmax, w2, w1,
                                                      cnt_g, list_g, out, 1);
    } else {
        float* u3t = (float*)(ws + WS_U3T);
        k_transposeU3<<<1105, 256, 0, stream>>>(U3, u3t, y, cnt_g, list_g);
        k_main<<<dim3(C_ * EQ, E_), 256, 0, stream>>>(x, u3t, U2, U1, wmax, w2, w1,
                                                      cnt_g, list_g, out, 0);
    }
}